// Round 1
// baseline (9801.238 us; speedup 1.0000x reference)
//
#include <hip/hip_runtime.h>

#define FF 512
#define HH 1024
#define LL 128
#define BB 128
#define PP 1024

typedef short short8 __attribute__((ext_vector_type(8)));
typedef float floatx4 __attribute__((ext_vector_type(4)));
typedef unsigned short ushort_t;

__device__ __forceinline__ float sigm(float x) {
    return 1.0f / (1.0f + __expf(-x));
}
// overflow-safe tanh: exp(-2|x|) underflows to 0 for large |x| -> +-1
__device__ __forceinline__ float tanh_fast(float x) {
    float ax = fabsf(x);
    float e = __expf(-2.0f * ax);
    float r = (1.0f - e) / (1.0f + e);
    return copysignf(r, x);
}

__device__ __forceinline__ unsigned short bf16_rtne(float x) {
    unsigned int u = __float_as_uint(x);
    return (unsigned short)((u + 0x7FFFu + ((u >> 16) & 1u)) >> 16);
}
__device__ __forceinline__ void split_bf16(float x, unsigned short& hi, unsigned short& lo) {
    hi = bf16_rtne(x);
    float hf = __uint_as_float(((unsigned int)hi) << 16);
    lo = bf16_rtne(x - hf);
}

__global__ void fillz(float* p, int n) {
    int i = blockIdx.x * blockDim.x + threadIdx.x;
    if (i < n) p[i] = 0.0f;
}

// fp32 [n] -> bf16 hi/lo [n]
__global__ void split_w(const float* __restrict__ W, ushort_t* __restrict__ hi,
                        ushort_t* __restrict__ lo, int n) {
    int i = blockIdx.x * blockDim.x + threadIdx.x;
    if (i < n) {
        unsigned short h, l;
        split_bf16(W[i], h, l);
        hi[i] = h; lo[i] = l;
    }
}

// ---------------------------------------------------------------------------
// bf16-split MFMA LSTM step, v3 (single-barrier double-buffered A staging):
//   g = init + h @ W_hh^T  via  h_hi*W_hi + h_lo*W_hi + h_hi*W_lo.
// - A (shared by all 4 waves) double-buffered in LDS: 2 x 16 KB. ONE
//   __syncthreads per K-chunk (was two): issue global A+B prefetch for
//   chunk kc+1, compute chunk kc from LDS buf[cur], THEN write prefetch
//   into buf[nxt] (vmcnt drain hidden under the 48-MFMA compute), barrier.
// - B (W rows) loaded DIRECT global->fragment registers, double-buffered;
//   reg-destined loads are waited at USE (next iter MFMA), so they stay in
//   flight across the barrier.
// - rotate swizzle (slot+row)&7 -> conflict-free fragment reads.
// - 1D grid 256, XCD swizzle keeps each XCD's 2 MB W slice L2-resident.
// Block tile 64f x (32c x 4 gates); wave = gate; 4x2 subtiles 16x16x32.
// ---------------------------------------------------------------------------
__global__ __launch_bounds__(256, 1) void lstm_step_mfma(
    const float* __restrict__ h_in,      // fp32 [512][1024]
    const ushort_t* __restrict__ hhi,    // bf16 [512][1024]
    const ushort_t* __restrict__ hlo,
    float* __restrict__ h_out,
    ushort_t* __restrict__ hhi_o,
    ushort_t* __restrict__ hlo_o,
    float* __restrict__ c_st,            // fp32 [512][1024]
    const ushort_t* __restrict__ Whi,    // bf16 [4096][1024]
    const ushort_t* __restrict__ Wlo,
    const float* __restrict__ initE,     // embW [128][4096] or u_p [512][4096]
    const int* __restrict__ tokens,      // [512][128] or null
    const int* __restrict__ lengths,     // [512] or null
    int t)
{
    __shared__ __align__(16) char smem[36864];
    // main loop: buf0 hi @0, buf0 lo @8192, buf1 hi @16384, buf1 lo @24576
    float* Gx = (float*)smem;            // epilogue reuse: [4][64][36] fp32

    const int tid = threadIdx.x;
    const int w = tid >> 6;              // wave index = gate
    const int l = tid & 63;
    const int q = l >> 4;                // k-quad 0..3
    const int fr = l & 15;               // fragment row/col

    // XCD-aware decode: xcd = id&7; by in {xcd, xcd+8, xcd+16, xcd+24}
    const int id = blockIdx.x;
    const int by = (id & 7) + 8 * ((id >> 3) & 3);
    const int bx = id >> 5;
    const int fbase = bx * 64;
    const int n0 = by * 32;

    // --- A staging map: thread -> row ar, logical slots s0=tid&3, s0+4 ---
    const int ar = tid >> 2;
    const int s0 = tid & 3;
    const size_t a_goff = (size_t)(fbase + ar) * HH + s0 * 8;   // +32 for s0+4
    const int sw0 = (s0 + ar) & 7;            // swizzled slot for s0
    const int sw1 = ((s0 + 4) + ar) & 7;      // swizzled slot for s0+4
    const int lds0 = ar * 8 + sw0;            // int4 index within a buffer half
    const int lds1 = ar * 8 + sw1;

    // --- B direct-fragment bases: wave w, subtile n, lane (fr,q) ---
    const size_t brow0 = ((size_t)(w * HH) + n0 + 0 * 16 + fr) * HH + q * 8;
    const size_t brow1 = ((size_t)(w * HH) + n0 + 1 * 16 + fr) * HH + q * 8;

    floatx4 acc[4][2];
    #pragma unroll
    for (int m = 0; m < 4; ++m)
        #pragma unroll
        for (int n = 0; n < 2; ++n) acc[m][n] = (floatx4)(0.0f);

    // prologue: A chunk 0 -> regs -> LDS buf0
    int4 pa_h0 = *(const int4*)(hhi + a_goff);
    int4 pa_h1 = *(const int4*)(hhi + a_goff + 32);
    int4 pa_l0 = *(const int4*)(hlo + a_goff);
    int4 pa_l1 = *(const int4*)(hlo + a_goff + 32);

    // B double buffer: [buf][n][kk]
    short8 Bh[2][2][2], Bl[2][2][2];
    #pragma unroll
    for (int kk = 0; kk < 2; ++kk) {
        Bh[0][0][kk] = *(const short8*)(Whi + brow0 + kk * 32);
        Bh[0][1][kk] = *(const short8*)(Whi + brow1 + kk * 32);
        Bl[0][0][kk] = *(const short8*)(Wlo + brow0 + kk * 32);
        Bl[0][1][kk] = *(const short8*)(Wlo + brow1 + kk * 32);
    }

    ((int4*)smem)[lds0] = pa_h0;
    ((int4*)smem)[lds1] = pa_h1;
    ((int4*)(smem + 8192))[lds0] = pa_l0;
    ((int4*)(smem + 8192))[lds1] = pa_l1;
    __syncthreads();

    #pragma unroll 2
    for (int kc = 0; kc < 16; ++kc) {
        const int cur = kc & 1, nxt = cur ^ 1;
        const char* AsH = smem + cur * 16384;
        const char* AsL = AsH + 8192;

        // issue prefetch for chunk kc+1 (global -> regs); latency hides
        // under the MFMA block below
        if (kc < 15) {
            const int k0 = (kc + 1) * 64;
            pa_h0 = *(const int4*)(hhi + a_goff + k0);
            pa_h1 = *(const int4*)(hhi + a_goff + k0 + 32);
            pa_l0 = *(const int4*)(hlo + a_goff + k0);
            pa_l1 = *(const int4*)(hlo + a_goff + k0 + 32);
            #pragma unroll
            for (int kk = 0; kk < 2; ++kk) {
                Bh[nxt][0][kk] = *(const short8*)(Whi + brow0 + k0 + kk * 32);
                Bh[nxt][1][kk] = *(const short8*)(Whi + brow1 + k0 + kk * 32);
                Bl[nxt][0][kk] = *(const short8*)(Wlo + brow0 + k0 + kk * 32);
                Bl[nxt][1][kk] = *(const short8*)(Wlo + brow1 + k0 + kk * 32);
            }
        }

        // compute chunk kc from buf[cur]
        #pragma unroll
        for (int m = 0; m < 4; ++m) {
            const int r = m * 16 + fr;
            short8 ah0 = *(const short8*)(AsH + (r * 8 + ((0 * 4 + q + r) & 7)) * 16);
            short8 ah1 = *(const short8*)(AsH + (r * 8 + ((1 * 4 + q + r) & 7)) * 16);
            short8 al0 = *(const short8*)(AsL + (r * 8 + ((0 * 4 + q + r) & 7)) * 16);
            short8 al1 = *(const short8*)(AsL + (r * 8 + ((1 * 4 + q + r) & 7)) * 16);
            #pragma unroll
            for (int n = 0; n < 2; ++n) {
                acc[m][n] = __builtin_amdgcn_mfma_f32_16x16x32_bf16(ah0, Bh[cur][n][0], acc[m][n], 0, 0, 0);
                acc[m][n] = __builtin_amdgcn_mfma_f32_16x16x32_bf16(al0, Bh[cur][n][0], acc[m][n], 0, 0, 0);
                acc[m][n] = __builtin_amdgcn_mfma_f32_16x16x32_bf16(ah0, Bl[cur][n][0], acc[m][n], 0, 0, 0);
                acc[m][n] = __builtin_amdgcn_mfma_f32_16x16x32_bf16(ah1, Bh[cur][n][1], acc[m][n], 0, 0, 0);
                acc[m][n] = __builtin_amdgcn_mfma_f32_16x16x32_bf16(al1, Bh[cur][n][1], acc[m][n], 0, 0, 0);
                acc[m][n] = __builtin_amdgcn_mfma_f32_16x16x32_bf16(ah1, Bl[cur][n][1], acc[m][n], 0, 0, 0);
            }
        }

        // write prefetched A chunk into buf[nxt] AFTER compute: the vmcnt
        // wait for pa_* lands here, hidden by ~48 MFMAs of latency.
        // buf[nxt] was last READ at iteration kc-1 (protected by that
        // iteration's barrier), so the write is race-free.
        if (kc < 15) {
            char* DH = smem + nxt * 16384;
            ((int4*)DH)[lds0] = pa_h0;
            ((int4*)DH)[lds1] = pa_h1;
            ((int4*)(DH + 8192))[lds0] = pa_l0;
            ((int4*)(DH + 8192))[lds1] = pa_l1;
        }
        __syncthreads();
    }

    // --- gate exchange (C/D layout: col = fr, row = q*4 + reg); stride 36 ---
    // loop ended with a barrier: all LDS fragment reads are complete, so
    // Gx (aliasing both A buffers) can be written directly.
    #pragma unroll
    for (int m = 0; m < 4; ++m)
        #pragma unroll
        for (int n = 0; n < 2; ++n)
            #pragma unroll
            for (int r = 0; r < 4; ++r)
                Gx[(w * 64 + m * 16 + q * 4 + r) * 36 + n * 16 + fr] = acc[m][n][r];
    __syncthreads();

    // --- fused cell update: thread -> (row rr, 8 consecutive cols) ---
    const int rr = tid >> 2;
    const int c0 = (tid & 3) * 8;
    const int f = fbase + rr;
    const int gc = n0 + c0;
    const size_t gidx = (size_t)f * HH + gc;
    const float* ib = tokens ? (initE + (size_t)tokens[f * LL + t] * 4096)
                             : (initE + (size_t)f * 4096);
    const bool upd = lengths ? (t < lengths[f]) : true;

    float4 gv[4][2];
    #pragma unroll
    for (int g = 0; g < 4; ++g) {
        gv[g][0] = *(const float4*)&Gx[(g * 64 + rr) * 36 + c0];
        gv[g][1] = *(const float4*)&Gx[(g * 64 + rr) * 36 + c0 + 4];
        const float4 ibv0 = *(const float4*)(ib + g * 1024 + gc);
        const float4 ibv1 = *(const float4*)(ib + g * 1024 + gc + 4);
        gv[g][0].x += ibv0.x; gv[g][0].y += ibv0.y; gv[g][0].z += ibv0.z; gv[g][0].w += ibv0.w;
        gv[g][1].x += ibv1.x; gv[g][1].y += ibv1.y; gv[g][1].z += ibv1.z; gv[g][1].w += ibv1.w;
    }
    float4 coldv[2] = { *(const float4*)(c_st + gidx), *(const float4*)(c_st + gidx + 4) };
    float4 holdv[2] = { *(const float4*)(h_in + gidx), *(const float4*)(h_in + gidx + 4) };

    float4 cw[2], hw[2];
    int4 hiv, lov;
    #pragma unroll
    for (int hf = 0; hf < 2; ++hf) {
        const float* gi = (const float*)&gv[0][hf];
        const float* gf = (const float*)&gv[1][hf];
        const float* gg = (const float*)&gv[2][hf];
        const float* go = (const float*)&gv[3][hf];
        const float* co = (const float*)&coldv[hf];
        const float* ho = (const float*)&holdv[hf];
        #pragma unroll
        for (int j = 0; j < 4; ++j) {
            float cn = sigm(gf[j]) * co[j] + sigm(gi[j]) * tanh_fast(gg[j]);
            float hn = sigm(go[j]) * tanh_fast(cn);
            float cv = upd ? cn : co[j];
            float hv = upd ? hn : ho[j];
            ((float*)&cw[hf])[j] = cv;
            ((float*)&hw[hf])[j] = hv;
            unsigned short hb, lb;
            split_bf16(hv, hb, lb);
            ((ushort_t*)&hiv)[hf * 4 + j] = hb;
            ((ushort_t*)&lov)[hf * 4 + j] = lb;
        }
    }
    *(float4*)(c_st + gidx) = cw[0];
    *(float4*)(c_st + gidx + 4) = cw[1];
    *(float4*)(h_out + gidx) = hw[0];
    *(float4*)(h_out + gidx + 4) = hw[1];
    *(int4*)(hhi_o + gidx) = hiv;
    *(int4*)(hlo_o + gidx) = lov;
}

// ---------------------------------------------------------------------------
// Generic fp32 C[M][N] = A[M][K] @ W[N][K]^T + bias[N]
// grid (M/32, N/64), block 256; per thread 4x2.
// ---------------------------------------------------------------------------
__global__ __launch_bounds__(256) void gemm_bias(
    const float* __restrict__ A, const float* __restrict__ W,
    const float* __restrict__ bias, float* __restrict__ C,
    int N, int K)
{
    __shared__ __align__(16) float As[16][32];
    __shared__ __align__(16) float Bs[16][64];
    const int tid = threadIdx.x;
    const int tm = tid & 7;
    const int tn = tid >> 3;
    const int m0 = blockIdx.x * 32, n0 = blockIdx.y * 64;
    const int am = tid >> 3;
    const int ak = (tid & 7) * 2;
    const int br = tid >> 2;
    const int bk = (tid & 3) * 4;
    const float* arow = A + (size_t)(m0 + am) * K;
    const float* brow = W + (size_t)(n0 + br) * K;
    float acc[4][2] = {};
    const int tm4 = tm * 4, tn2 = tn * 2;

    for (int k0 = 0; k0 < K; k0 += 16) {
        __syncthreads();
        float2 av = *(const float2*)(arow + k0 + ak);
        float4 bv = *(const float4*)(brow + k0 + bk);
        As[ak][am] = av.x; As[ak + 1][am] = av.y;
        Bs[bk][br] = bv.x; Bs[bk + 1][br] = bv.y;
        Bs[bk + 2][br] = bv.z; Bs[bk + 3][br] = bv.w;
        __syncthreads();
        #pragma unroll
        for (int k = 0; k < 16; ++k) {
            float4 a = *(const float4*)&As[k][tm4];
            float2 b = *(const float2*)&Bs[k][tn2];
            acc[0][0] += a.x * b.x; acc[0][1] += a.x * b.y;
            acc[1][0] += a.y * b.x; acc[1][1] += a.y * b.y;
            acc[2][0] += a.z * b.x; acc[2][1] += a.z * b.y;
            acc[3][0] += a.w * b.x; acc[3][1] += a.w * b.y;
        }
    }
    float b0 = bias[n0 + tn2], b1 = bias[n0 + tn2 + 1];
    #pragma unroll
    for (int mi = 0; mi < 4; ++mi) {
        float2 o;
        o.x = acc[mi][0] + b0;
        o.y = acc[mi][1] + b1;
        *(float2*)(C + (size_t)(m0 + tm4 + mi) * N + n0 + tn2) = o;
    }
}

// ---------------------------------------------------------------------------
// pooled[b][n] = tanh(max_e (h[4b+e] @ W_mp^T) + b_mp)   (tanh monotone)
// ---------------------------------------------------------------------------
__global__ __launch_bounds__(256) void mp_pool(
    const float* __restrict__ h, const float* __restrict__ Wmp,
    const float* __restrict__ bmp, float* __restrict__ pooled)
{
    __shared__ __align__(16) float As[16][32];
    __shared__ __align__(16) float Bs[16][64];
    const int tid = threadIdx.x;
    const int tm = tid & 7;
    const int tn = tid >> 3;
    const int m0 = blockIdx.x * 32, n0 = blockIdx.y * 64;
    const int am = tid >> 3;
    const int ak = (tid & 7) * 2;
    const int br = tid >> 2;
    const int bk = (tid & 3) * 4;
    const float* arow = h + (size_t)(m0 + am) * HH;
    const float* brow = Wmp + (size_t)(n0 + br) * HH;
    float acc[4][2] = {};
    const int tm4 = tm * 4, tn2 = tn * 2;

    for (int k0 = 0; k0 < HH; k0 += 16) {
        __syncthreads();
        float2 av = *(const float2*)(arow + k0 + ak);
        float4 bv = *(const float4*)(brow + k0 + bk);
        As[ak][am] = av.x; As[ak + 1][am] = av.y;
        Bs[bk][br] = bv.x; Bs[bk + 1][br] = bv.y;
        Bs[bk + 2][br] = bv.z; Bs[bk + 3][br] = bv.w;
        __syncthreads();
        #pragma unroll
        for (int k = 0; k < 16; ++k) {
            float4 a = *(const float4*)&As[k][tm4];
            float2 b = *(const float2*)&Bs[k][tn2];
            acc[0][0] += a.x * b.x; acc[0][1] += a.x * b.y;
            acc[1][0] += a.y * b.x; acc[1][1] += a.y * b.y;
            acc[2][0] += a.z * b.x; acc[2][1] += a.z * b.y;
            acc[3][0] += a.w * b.x; acc[3][1] += a.w * b.y;
        }
    }
    float mx0 = fmaxf(fmaxf(acc[0][0], acc[1][0]), fmaxf(acc[2][0], acc[3][0]));
    float mx1 = fmaxf(fmaxf(acc[0][1], acc[1][1]), fmaxf(acc[2][1], acc[3][1]));
    mx0 += bmp[n0 + tn2];
    mx1 += bmp[n0 + tn2 + 1];
    float2 o;
    o.x = tanh_fast(mx0);
    o.y = tanh_fast(mx1);
    const int bidx = (m0 >> 2) + tm;
    *(float2*)(pooled + (size_t)bidx * HH + n0 + tn2) = o;
}

extern "C" void kernel_launch(void* const* d_in, const int* in_sizes, int n_in,
                              void* d_out, int out_size, void* d_ws, size_t ws_size,
                              hipStream_t stream)
{
    const int*   tokens_in   = (const int*)d_in[0];
    const int*   lengths_in  = (const int*)d_in[1];
    const int*   tokens_out  = (const int*)d_in[2];
    const int*   lengths_out = (const int*)d_in[3];
    const float* embedding   = (const float*)d_in[4];
    const float* W_ih_in     = (const float*)d_in[5];
    const float* W_hh_in     = (const float*)d_in[6];
    const float* b_in        = (const float*)d_in[7];
    const float* W_ih_out    = (const float*)d_in[8];
    const float* W_hh_out    = (const float*)d_in[9];
    const float* b_out       = (const float*)d_in[10];
    const float* W_ih_p      = (const float*)d_in[11];
    const float* W_hh_p      = (const float*)d_in[12];
    const float* b_p         = (const float*)d_in[13];
    const float* W_mp        = (const float*)d_in[14];
    const float* b_mp        = (const float*)d_in[15];
    const float* W_sm        = (const float*)d_in[16];
    const float* b_sm        = (const float*)d_in[17];
    float* out = (float*)d_out;

    // workspace layout (float units); total ~18.5M floats = 74 MB
    float* ws = (float*)d_ws;
    float* h_a      = ws;                  // 524288
    float* h_b      = ws + 524288;         // 524288
    float* c_st     = ws + 1048576;        // 524288
    float* embW_in  = ws + 1572864;        // 524288
    float* embW_out = ws + 2097152;        // 524288
    float* u_p      = ws + 2621440;        // 2097152
    float* pooled   = ws + 4718592;        // 131072
    ushort_t* hhi_a = (ushort_t*)(ws + 4849664);   // 524288 bf16
    ushort_t* hlo_a = (ushort_t*)(ws + 5111808);
    ushort_t* hhi_b = (ushort_t*)(ws + 5373952);
    ushort_t* hlo_b = (ushort_t*)(ws + 5636096);
    ushort_t* Whi_in  = (ushort_t*)(ws + 5898240); // 4194304 bf16 each
    ushort_t* Wlo_in  = (ushort_t*)(ws + 7995392);
    ushort_t* Whi_out = (ushort_t*)(ws + 10092544);
    ushort_t* Wlo_out = (ushort_t*)(ws + 12189696);
    ushort_t* Whi_p   = (ushort_t*)(ws + 14286848);
    ushort_t* Wlo_p   = (ushort_t*)(ws + 16384000);

    // zero h0, c0, and h0's bf16 hi/lo (hhi_a/hlo_a are adjacent)
    fillz<<<2048, 256, 0, stream>>>(h_a, 524288);
    fillz<<<2048, 256, 0, stream>>>(c_st, 524288);
    fillz<<<2048, 256, 0, stream>>>(ws + 4849664, 524288);

    // split the three recurrent weight matrices into bf16 hi/lo
    split_w<<<16384, 256, 0, stream>>>(W_hh_in,  Whi_in,  Wlo_in,  4194304);
    split_w<<<16384, 256, 0, stream>>>(W_hh_out, Whi_out, Wlo_out, 4194304);
    split_w<<<16384, 256, 0, stream>>>(W_hh_p,   Whi_p,   Wlo_p,   4194304);

    // embW = embedding @ W_ih^T + b  (x @ W_ih collapses to a gather)
    gemm_bias<<<dim3(4, 64), 256, 0, stream>>>(embedding, W_ih_in, b_in, embW_in, 4096, 128);
    gemm_bias<<<dim3(4, 64), 256, 0, stream>>>(embedding, W_ih_out, b_out, embW_out, 4096, 128);

    float* hc = h_a;  ushort_t* hic = hhi_a;  ushort_t* loc = hlo_a;
    float* hn = h_b;  ushort_t* hin = hhi_b;  ushort_t* lon = hlo_b;

    for (int t = 0; t < 128; ++t) {
        lstm_step_mfma<<<256, 256, 0, stream>>>(
            hc, hic, loc, hn, hin, lon, c_st, Whi_in, Wlo_in, embW_in,
            tokens_in, lengths_in, t);
        float* tf = hc; hc = hn; hn = tf;
        ushort_t* th = hic; hic = hin; hin = th;
        ushort_t* tl = loc; loc = lon; lon = tl;
    }
    for (int t = 0; t < 128; ++t) {
        lstm_step_mfma<<<256, 256, 0, stream>>>(
            hc, hic, loc, hn, hin, lon, c_st, Whi_out, Wlo_out, embW_out,
            tokens_out, lengths_out, t);
        float* tf = hc; hc = hn; hn = tf;
        ushort_t* th = hic; hic = hin; hin = th;
        ushort_t* tl = loc; loc = lon; lon = tl;
    }

    // u_p = prev_h @ W_ih_p^T + b_p  (prev_h constant across all 16 steps)
    gemm_bias<<<dim3(16, 64), 256, 0, stream>>>(hc, W_ih_p, b_p, u_p, 4096, 1024);

    for (int t = 0; t < 16; ++t) {
        lstm_step_mfma<<<256, 256, 0, stream>>>(
            hc, hic, loc, hn, hin, lon, c_st, Whi_p, Wlo_p, u_p,
            nullptr, nullptr, t);
        mp_pool<<<dim3(16, 16), 256, 0, stream>>>(hn, W_mp, b_mp, pooled);
        gemm_bias<<<dim3(4, 16), 256, 0, stream>>>(pooled, W_sm, b_sm,
                                                   out + (size_t)t * (BB * PP), 1024, 1024);
        float* tf = hc; hc = hn; hn = tf;
        ushort_t* th = hic; hic = hin; hin = th;
        ushort_t* tl = loc; loc = lon; lon = tl;
    }
}

// Round 2
// 8526.134 us; speedup vs baseline: 1.1496x; 1.1496x over previous
//
#include <hip/hip_runtime.h>

#define FF 512
#define HH 1024
#define LL 128
#define BB 128
#define PP 1024

typedef short short8 __attribute__((ext_vector_type(8)));
typedef float floatx4 __attribute__((ext_vector_type(4)));
typedef unsigned short ushort_t;

__device__ __forceinline__ float sigm(float x) {
    return 1.0f / (1.0f + __expf(-x));
}
// overflow-safe tanh: exp(-2|x|) underflows to 0 for large |x| -> +-1
__device__ __forceinline__ float tanh_fast(float x) {
    float ax = fabsf(x);
    float e = __expf(-2.0f * ax);
    float r = (1.0f - e) / (1.0f + e);
    return copysignf(r, x);
}

__device__ __forceinline__ unsigned short bf16_rtne(float x) {
    unsigned int u = __float_as_uint(x);
    return (unsigned short)((u + 0x7FFFu + ((u >> 16) & 1u)) >> 16);
}
__device__ __forceinline__ void split_bf16(float x, unsigned short& hi, unsigned short& lo) {
    hi = bf16_rtne(x);
    float hf = __uint_as_float(((unsigned int)hi) << 16);
    lo = bf16_rtne(x - hf);
}

__global__ void fillz(float* p, int n) {
    int i = blockIdx.x * blockDim.x + threadIdx.x;
    if (i < n) p[i] = 0.0f;
}

// fp32 [n] -> bf16 hi/lo [n]
__global__ void split_w(const float* __restrict__ W, ushort_t* __restrict__ hi,
                        ushort_t* __restrict__ lo, int n) {
    int i = blockIdx.x * blockDim.x + threadIdx.x;
    if (i < n) {
        unsigned short h, l;
        split_bf16(W[i], h, l);
        hi[i] = h; lo[i] = l;
    }
}

// ---------------------------------------------------------------------------
// bf16-split MFMA LSTM step, v4 (8-wave K-split):
//   g = init + h @ W_hh^T  via  h_hi*W_hi + h_lo*W_hi + h_hi*W_lo.
// - 256 blocks x 512 threads. Wave w: gate g=w&3, K-half kh=w>>2.
//   Group kh processes K-chunks [8kh, 8kh+8); partial accumulators reduced
//   via the Gx LDS exchange (group1 writes, group0 adds). This gives
//   2 waves/SIMD (was 1): L2 load-return latency and dependent-MFMA chain
//   stalls are hidden by the co-resident wave; per-wave critical path is
//   halved (8 kc + ~10 barriers vs 16 kc + 19). L2 traffic, MFMA count,
//   and tiling are UNCHANGED vs v3.
// - A (shared by the 4 gate-waves of a group) in LDS: 4 regions of 16 KB
//   (per group: double-buffered hi+lo). ONE __syncthreads per chunk:
//   prefetch -> compute -> LDS-write (vmcnt drain hidden under 48 MFMAs)
//   -> barrier.
// - B (W rows) loaded DIRECT global->fragment registers, double-buffered.
// - rotate swizzle (slot+row)&7 -> conflict-free fragment reads.
// - 1D grid 256, XCD swizzle keeps each XCD's 2 MB W slice L2-resident.
// Block tile 64f x (32c x 4 gates); 4x2 subtiles 16x16x32 per wave.
// ---------------------------------------------------------------------------
__global__ __launch_bounds__(512, 2) void lstm_step_mfma(
    const float* __restrict__ h_in,      // fp32 [512][1024]
    const ushort_t* __restrict__ hhi,    // bf16 [512][1024]
    const ushort_t* __restrict__ hlo,
    float* __restrict__ h_out,
    ushort_t* __restrict__ hhi_o,
    ushort_t* __restrict__ hlo_o,
    float* __restrict__ c_st,            // fp32 [512][1024]
    const ushort_t* __restrict__ Whi,    // bf16 [4096][1024]
    const ushort_t* __restrict__ Wlo,
    const float* __restrict__ initE,     // embW [128][4096] or u_p [512][4096]
    const int* __restrict__ tokens,      // [512][128] or null
    const int* __restrict__ lengths,     // [512] or null
    int t)
{
    // A regions: (grp*2 + parity)*16384; within region hi @+0, lo @+8192.
    __shared__ __align__(16) char smem[65536];
    float* Gx = (float*)smem;            // epilogue reuse: [4][64][36] fp32

    const int tid = threadIdx.x;
    const int w = tid >> 6;              // wave 0..7
    const int g = w & 3;                 // gate
    const int kh = w >> 2;               // K-half 0/1
    const int l = tid & 63;
    const int q = l >> 4;                // k-quad 0..3
    const int fr = l & 15;               // fragment row/col

    // XCD-aware decode: xcd = id&7; by in {xcd, xcd+8, xcd+16, xcd+24}
    const int id = blockIdx.x;
    const int by = (id & 7) + 8 * ((id >> 3) & 3);
    const int bx = id >> 5;
    const int fbase = bx * 64;
    const int n0 = by * 32;

    // --- A staging map: half the threads per group chunk ---
    const int sgrp = tid >> 8;           // which group's chunk this thread stages
    const int u = tid & 255;
    const int ar = u >> 2;               // row 0..63
    const int s0 = u & 3;                // logical slots s0, s0+4
    const size_t a_goff = (size_t)(fbase + ar) * HH + s0 * 8 + sgrp * 512;
    const int sw0 = (s0 + ar) & 7;
    const int sw1 = ((s0 + 4) + ar) & 7;
    const int lds0 = ar * 8 + sw0;       // int4 index within a region half
    const int lds1 = ar * 8 + sw1;

    // --- B direct-fragment bases: gate g, K-half kh, subtile n, lane (fr,q)
    const size_t brow0 = ((size_t)(g * HH) + n0 + 0 * 16 + fr) * HH + q * 8 + kh * 512;
    const size_t brow1 = ((size_t)(g * HH) + n0 + 1 * 16 + fr) * HH + q * 8 + kh * 512;

    floatx4 acc[4][2];
    #pragma unroll
    for (int m = 0; m < 4; ++m)
        #pragma unroll
        for (int n = 0; n < 2; ++n) acc[m][n] = (floatx4)(0.0f);

    // prologue: stage chunk 0 of each group into region (sgrp, parity 0)
    int4 pa_h0 = *(const int4*)(hhi + a_goff);
    int4 pa_h1 = *(const int4*)(hhi + a_goff + 32);
    int4 pa_l0 = *(const int4*)(hlo + a_goff);
    int4 pa_l1 = *(const int4*)(hlo + a_goff + 32);

    // B double buffer: [buf][n][kk]
    short8 Bh[2][2][2], Bl[2][2][2];
    #pragma unroll
    for (int kk = 0; kk < 2; ++kk) {
        Bh[0][0][kk] = *(const short8*)(Whi + brow0 + kk * 32);
        Bh[0][1][kk] = *(const short8*)(Whi + brow1 + kk * 32);
        Bl[0][0][kk] = *(const short8*)(Wlo + brow0 + kk * 32);
        Bl[0][1][kk] = *(const short8*)(Wlo + brow1 + kk * 32);
    }

    {
        char* R0 = smem + sgrp * 32768;
        ((int4*)R0)[lds0] = pa_h0;
        ((int4*)R0)[lds1] = pa_h1;
        ((int4*)(R0 + 8192))[lds0] = pa_l0;
        ((int4*)(R0 + 8192))[lds1] = pa_l1;
    }
    __syncthreads();

    #pragma unroll 2
    for (int i = 0; i < 8; ++i) {
        const int cur = i & 1, nxt = cur ^ 1;
        const char* AsH = smem + (kh * 2 + cur) * 16384;
        const char* AsL = AsH + 8192;

        // issue prefetch for local chunk i+1 (global -> regs)
        if (i < 7) {
            const int k0 = (i + 1) * 64;
            pa_h0 = *(const int4*)(hhi + a_goff + k0);
            pa_h1 = *(const int4*)(hhi + a_goff + k0 + 32);
            pa_l0 = *(const int4*)(hlo + a_goff + k0);
            pa_l1 = *(const int4*)(hlo + a_goff + k0 + 32);
            #pragma unroll
            for (int kk = 0; kk < 2; ++kk) {
                Bh[nxt][0][kk] = *(const short8*)(Whi + brow0 + k0 + kk * 32);
                Bh[nxt][1][kk] = *(const short8*)(Whi + brow1 + k0 + kk * 32);
                Bl[nxt][0][kk] = *(const short8*)(Wlo + brow0 + k0 + kk * 32);
                Bl[nxt][1][kk] = *(const short8*)(Wlo + brow1 + k0 + kk * 32);
            }
        }

        // compute local chunk i from region (kh, cur)
        #pragma unroll
        for (int m = 0; m < 4; ++m) {
            const int r = m * 16 + fr;
            short8 ah0 = *(const short8*)(AsH + (r * 8 + ((0 * 4 + q + r) & 7)) * 16);
            short8 ah1 = *(const short8*)(AsH + (r * 8 + ((1 * 4 + q + r) & 7)) * 16);
            short8 al0 = *(const short8*)(AsL + (r * 8 + ((0 * 4 + q + r) & 7)) * 16);
            short8 al1 = *(const short8*)(AsL + (r * 8 + ((1 * 4 + q + r) & 7)) * 16);
            #pragma unroll
            for (int n = 0; n < 2; ++n) {
                acc[m][n] = __builtin_amdgcn_mfma_f32_16x16x32_bf16(ah0, Bh[cur][n][0], acc[m][n], 0, 0, 0);
                acc[m][n] = __builtin_amdgcn_mfma_f32_16x16x32_bf16(al0, Bh[cur][n][0], acc[m][n], 0, 0, 0);
                acc[m][n] = __builtin_amdgcn_mfma_f32_16x16x32_bf16(ah0, Bl[cur][n][0], acc[m][n], 0, 0, 0);
                acc[m][n] = __builtin_amdgcn_mfma_f32_16x16x32_bf16(ah1, Bh[cur][n][1], acc[m][n], 0, 0, 0);
                acc[m][n] = __builtin_amdgcn_mfma_f32_16x16x32_bf16(al1, Bh[cur][n][1], acc[m][n], 0, 0, 0);
                acc[m][n] = __builtin_amdgcn_mfma_f32_16x16x32_bf16(ah1, Bl[cur][n][1], acc[m][n], 0, 0, 0);
            }
        }

        // write prefetched chunk into region (sgrp, nxt) AFTER compute:
        // the vmcnt wait for pa_* is hidden by ~48 MFMAs. Region (sgrp,nxt)
        // was last READ at iteration i-1 (protected by that barrier).
        if (i < 7) {
            char* DH = smem + (sgrp * 2 + nxt) * 16384;
            ((int4*)DH)[lds0] = pa_h0;
            ((int4*)DH)[lds1] = pa_h1;
            ((int4*)(DH + 8192))[lds0] = pa_l0;
            ((int4*)(DH + 8192))[lds1] = pa_l1;
        }
        __syncthreads();
    }

    // --- K-half reduce + gate exchange (C/D layout: col=fr, row=q*4+reg) ---
    // loop ended with a barrier: A regions are dead, Gx can alias them.
    if (kh == 1) {
        #pragma unroll
        for (int m = 0; m < 4; ++m)
            #pragma unroll
            for (int n = 0; n < 2; ++n)
                #pragma unroll
                for (int r = 0; r < 4; ++r)
                    Gx[(g * 64 + m * 16 + q * 4 + r) * 36 + n * 16 + fr] = acc[m][n][r];
    }
    __syncthreads();
    if (kh == 0) {
        #pragma unroll
        for (int m = 0; m < 4; ++m)
            #pragma unroll
            for (int n = 0; n < 2; ++n)
                #pragma unroll
                for (int r = 0; r < 4; ++r) {
                    const int idx = (g * 64 + m * 16 + q * 4 + r) * 36 + n * 16 + fr;
                    Gx[idx] += acc[m][n][r];
                }
    }
    __syncthreads();

    // --- fused cell update: thread -> (row rr, 4 consecutive cols) ---
    const int rr = tid >> 3;
    const int c0 = (tid & 7) * 4;
    const int f = fbase + rr;
    const int gc = n0 + c0;
    const size_t gidx = (size_t)f * HH + gc;
    const float* ib = tokens ? (initE + (size_t)tokens[f * LL + t] * 4096)
                             : (initE + (size_t)f * 4096);
    const bool upd = lengths ? (t < lengths[f]) : true;

    float4 gv[4];
    #pragma unroll
    for (int gg = 0; gg < 4; ++gg) {
        gv[gg] = *(const float4*)&Gx[(gg * 64 + rr) * 36 + c0];
        const float4 ibv = *(const float4*)(ib + gg * 1024 + gc);
        gv[gg].x += ibv.x; gv[gg].y += ibv.y; gv[gg].z += ibv.z; gv[gg].w += ibv.w;
    }
    const float4 coldv = *(const float4*)(c_st + gidx);
    const float4 holdv = *(const float4*)(h_in + gidx);

    float4 cw, hw;
    unsigned short hb[4], lb[4];
    {
        const float* gi = (const float*)&gv[0];
        const float* gf = (const float*)&gv[1];
        const float* gn = (const float*)&gv[2];
        const float* go = (const float*)&gv[3];
        const float* co = (const float*)&coldv;
        const float* ho = (const float*)&holdv;
        #pragma unroll
        for (int j = 0; j < 4; ++j) {
            float cn = sigm(gf[j]) * co[j] + sigm(gi[j]) * tanh_fast(gn[j]);
            float hn = sigm(go[j]) * tanh_fast(cn);
            float cv = upd ? cn : co[j];
            float hv = upd ? hn : ho[j];
            ((float*)&cw)[j] = cv;
            ((float*)&hw)[j] = hv;
            split_bf16(hv, hb[j], lb[j]);
        }
    }
    *(float4*)(c_st + gidx) = cw;
    *(float4*)(h_out + gidx) = hw;
    uint2 hp, lp;
    hp.x = (unsigned)hb[0] | ((unsigned)hb[1] << 16);
    hp.y = (unsigned)hb[2] | ((unsigned)hb[3] << 16);
    lp.x = (unsigned)lb[0] | ((unsigned)lb[1] << 16);
    lp.y = (unsigned)lb[2] | ((unsigned)lb[3] << 16);
    *(uint2*)(hhi_o + gidx) = hp;
    *(uint2*)(hlo_o + gidx) = lp;
}

// ---------------------------------------------------------------------------
// Generic fp32 C[M][N] = A[M][K] @ W[N][K]^T + bias[N]
// grid (M/32, N/64), block 256; per thread 4x2.
// ---------------------------------------------------------------------------
__global__ __launch_bounds__(256) void gemm_bias(
    const float* __restrict__ A, const float* __restrict__ W,
    const float* __restrict__ bias, float* __restrict__ C,
    int N, int K)
{
    __shared__ __align__(16) float As[16][32];
    __shared__ __align__(16) float Bs[16][64];
    const int tid = threadIdx.x;
    const int tm = tid & 7;
    const int tn = tid >> 3;
    const int m0 = blockIdx.x * 32, n0 = blockIdx.y * 64;
    const int am = tid >> 3;
    const int ak = (tid & 7) * 2;
    const int br = tid >> 2;
    const int bk = (tid & 3) * 4;
    const float* arow = A + (size_t)(m0 + am) * K;
    const float* brow = W + (size_t)(n0 + br) * K;
    float acc[4][2] = {};
    const int tm4 = tm * 4, tn2 = tn * 2;

    for (int k0 = 0; k0 < K; k0 += 16) {
        __syncthreads();
        float2 av = *(const float2*)(arow + k0 + ak);
        float4 bv = *(const float4*)(brow + k0 + bk);
        As[ak][am] = av.x; As[ak + 1][am] = av.y;
        Bs[bk][br] = bv.x; Bs[bk + 1][br] = bv.y;
        Bs[bk + 2][br] = bv.z; Bs[bk + 3][br] = bv.w;
        __syncthreads();
        #pragma unroll
        for (int k = 0; k < 16; ++k) {
            float4 a = *(const float4*)&As[k][tm4];
            float2 b = *(const float2*)&Bs[k][tn2];
            acc[0][0] += a.x * b.x; acc[0][1] += a.x * b.y;
            acc[1][0] += a.y * b.x; acc[1][1] += a.y * b.y;
            acc[2][0] += a.z * b.x; acc[2][1] += a.z * b.y;
            acc[3][0] += a.w * b.x; acc[3][1] += a.w * b.y;
        }
    }
    float b0 = bias[n0 + tn2], b1 = bias[n0 + tn2 + 1];
    #pragma unroll
    for (int mi = 0; mi < 4; ++mi) {
        float2 o;
        o.x = acc[mi][0] + b0;
        o.y = acc[mi][1] + b1;
        *(float2*)(C + (size_t)(m0 + tm4 + mi) * N + n0 + tn2) = o;
    }
}

// ---------------------------------------------------------------------------
// pooled[b][n] = tanh(max_e (h[4b+e] @ W_mp^T) + b_mp)   (tanh monotone)
// ---------------------------------------------------------------------------
__global__ __launch_bounds__(256) void mp_pool(
    const float* __restrict__ h, const float* __restrict__ Wmp,
    const float* __restrict__ bmp, float* __restrict__ pooled)
{
    __shared__ __align__(16) float As[16][32];
    __shared__ __align__(16) float Bs[16][64];
    const int tid = threadIdx.x;
    const int tm = tid & 7;
    const int tn = tid >> 3;
    const int m0 = blockIdx.x * 32, n0 = blockIdx.y * 64;
    const int am = tid >> 3;
    const int ak = (tid & 7) * 2;
    const int br = tid >> 2;
    const int bk = (tid & 3) * 4;
    const float* arow = h + (size_t)(m0 + am) * HH;
    const float* brow = Wmp + (size_t)(n0 + br) * HH;
    float acc[4][2] = {};
    const int tm4 = tm * 4, tn2 = tn * 2;

    for (int k0 = 0; k0 < HH; k0 += 16) {
        __syncthreads();
        float2 av = *(const float2*)(arow + k0 + ak);
        float4 bv = *(const float4*)(brow + k0 + bk);
        As[ak][am] = av.x; As[ak + 1][am] = av.y;
        Bs[bk][br] = bv.x; Bs[bk + 1][br] = bv.y;
        Bs[bk + 2][br] = bv.z; Bs[bk + 3][br] = bv.w;
        __syncthreads();
        #pragma unroll
        for (int k = 0; k < 16; ++k) {
            float4 a = *(const float4*)&As[k][tm4];
            float2 b = *(const float2*)&Bs[k][tn2];
            acc[0][0] += a.x * b.x; acc[0][1] += a.x * b.y;
            acc[1][0] += a.y * b.x; acc[1][1] += a.y * b.y;
            acc[2][0] += a.z * b.x; acc[2][1] += a.z * b.y;
            acc[3][0] += a.w * b.x; acc[3][1] += a.w * b.y;
        }
    }
    float mx0 = fmaxf(fmaxf(acc[0][0], acc[1][0]), fmaxf(acc[2][0], acc[3][0]));
    float mx1 = fmaxf(fmaxf(acc[0][1], acc[1][1]), fmaxf(acc[2][1], acc[3][1]));
    mx0 += bmp[n0 + tn2];
    mx1 += bmp[n0 + tn2 + 1];
    float2 o;
    o.x = tanh_fast(mx0);
    o.y = tanh_fast(mx1);
    const int bidx = (m0 >> 2) + tm;
    *(float2*)(pooled + (size_t)bidx * HH + n0 + tn2) = o;
}

extern "C" void kernel_launch(void* const* d_in, const int* in_sizes, int n_in,
                              void* d_out, int out_size, void* d_ws, size_t ws_size,
                              hipStream_t stream)
{
    const int*   tokens_in   = (const int*)d_in[0];
    const int*   lengths_in  = (const int*)d_in[1];
    const int*   tokens_out  = (const int*)d_in[2];
    const int*   lengths_out = (const int*)d_in[3];
    const float* embedding   = (const float*)d_in[4];
    const float* W_ih_in     = (const float*)d_in[5];
    const float* W_hh_in     = (const float*)d_in[6];
    const float* b_in        = (const float*)d_in[7];
    const float* W_ih_out    = (const float*)d_in[8];
    const float* W_hh_out    = (const float*)d_in[9];
    const float* b_out       = (const float*)d_in[10];
    const float* W_ih_p      = (const float*)d_in[11];
    const float* W_hh_p      = (const float*)d_in[12];
    const float* b_p         = (const float*)d_in[13];
    const float* W_mp        = (const float*)d_in[14];
    const float* b_mp        = (const float*)d_in[15];
    const float* W_sm        = (const float*)d_in[16];
    const float* b_sm        = (const float*)d_in[17];
    float* out = (float*)d_out;

    // workspace layout (float units); total ~18.5M floats = 74 MB
    float* ws = (float*)d_ws;
    float* h_a      = ws;                  // 524288
    float* h_b      = ws + 524288;         // 524288
    float* c_st     = ws + 1048576;        // 524288
    float* embW_in  = ws + 1572864;        // 524288
    float* embW_out = ws + 2097152;        // 524288
    float* u_p      = ws + 2621440;        // 2097152
    float* pooled   = ws + 4718592;        // 131072
    ushort_t* hhi_a = (ushort_t*)(ws + 4849664);   // 524288 bf16
    ushort_t* hlo_a = (ushort_t*)(ws + 5111808);
    ushort_t* hhi_b = (ushort_t*)(ws + 5373952);
    ushort_t* hlo_b = (ushort_t*)(ws + 5636096);
    ushort_t* Whi_in  = (ushort_t*)(ws + 5898240); // 4194304 bf16 each
    ushort_t* Wlo_in  = (ushort_t*)(ws + 7995392);
    ushort_t* Whi_out = (ushort_t*)(ws + 10092544);
    ushort_t* Wlo_out = (ushort_t*)(ws + 12189696);
    ushort_t* Whi_p   = (ushort_t*)(ws + 14286848);
    ushort_t* Wlo_p   = (ushort_t*)(ws + 16384000);

    // zero h0, c0, and h0's bf16 hi/lo (hhi_a/hlo_a are adjacent)
    fillz<<<2048, 256, 0, stream>>>(h_a, 524288);
    fillz<<<2048, 256, 0, stream>>>(c_st, 524288);
    fillz<<<2048, 256, 0, stream>>>(ws + 4849664, 524288);

    // split the three recurrent weight matrices into bf16 hi/lo
    split_w<<<16384, 256, 0, stream>>>(W_hh_in,  Whi_in,  Wlo_in,  4194304);
    split_w<<<16384, 256, 0, stream>>>(W_hh_out, Whi_out, Wlo_out, 4194304);
    split_w<<<16384, 256, 0, stream>>>(W_hh_p,   Whi_p,   Wlo_p,   4194304);

    // embW = embedding @ W_ih^T + b  (x @ W_ih collapses to a gather)
    gemm_bias<<<dim3(4, 64), 256, 0, stream>>>(embedding, W_ih_in, b_in, embW_in, 4096, 128);
    gemm_bias<<<dim3(4, 64), 256, 0, stream>>>(embedding, W_ih_out, b_out, embW_out, 4096, 128);

    float* hc = h_a;  ushort_t* hic = hhi_a;  ushort_t* loc = hlo_a;
    float* hn = h_b;  ushort_t* hin = hhi_b;  ushort_t* lon = hlo_b;

    for (int t = 0; t < 128; ++t) {
        lstm_step_mfma<<<256, 512, 0, stream>>>(
            hc, hic, loc, hn, hin, lon, c_st, Whi_in, Wlo_in, embW_in,
            tokens_in, lengths_in, t);
        float* tf = hc; hc = hn; hn = tf;
        ushort_t* th = hic; hic = hin; hin = th;
        ushort_t* tl = loc; loc = lon; lon = tl;
    }
    for (int t = 0; t < 128; ++t) {
        lstm_step_mfma<<<256, 512, 0, stream>>>(
            hc, hic, loc, hn, hin, lon, c_st, Whi_out, Wlo_out, embW_out,
            tokens_out, lengths_out, t);
        float* tf = hc; hc = hn; hn = tf;
        ushort_t* th = hic; hic = hin; hin = th;
        ushort_t* tl = loc; loc = lon; lon = tl;
    }

    // u_p = prev_h @ W_ih_p^T + b_p  (prev_h constant across all 16 steps)
    gemm_bias<<<dim3(16, 64), 256, 0, stream>>>(hc, W_ih_p, b_p, u_p, 4096, 1024);

    for (int t = 0; t < 16; ++t) {
        lstm_step_mfma<<<256, 512, 0, stream>>>(
            hc, hic, loc, hn, hin, lon, c_st, Whi_p, Wlo_p, u_p,
            nullptr, nullptr, t);
        mp_pool<<<dim3(16, 16), 256, 0, stream>>>(hn, W_mp, b_mp, pooled);
        gemm_bias<<<dim3(4, 16), 256, 0, stream>>>(pooled, W_sm, b_sm,
                                                   out + (size_t)t * (BB * PP), 1024, 1024);
        float* tf = hc; hc = hn; hn = tf;
        ushort_t* th = hic; hic = hin; hin = th;
        ushort_t* tl = loc; loc = lon; lon = tl;
    }
}